// Round 1
// baseline (1980.677 us; speedup 1.0000x reference)
//
#include <hip/hip_runtime.h>
#include <cstdint>
#include <cstddef>

// LSTM: B=256, S=512, C=64, H=128, 2 layers, torch gate order i,f,g,o.
// Design: per-layer persistent recurrence kernel, 16 blocks x 512 threads
// (8 waves). Block owns 16 batch rows for all 512 steps. Weights live in
// per-wave VGPR B-fragments (bf16), loaded once. Input GEMM fused into the
// step (gates = bias + h*Whh^T + x_t*Wih^T). h exchanged via 4KB LDS buffer
// in a chunk-swizzled layout so A-frag reads are consecutive ds_read_b128.
// c-state stays in fp32 registers in the MFMA C/D layout across steps.

#define S_LEN 512
#define B_SZ  256
#define C_IN  64
#define HDIM  128

using short8  = __attribute__((ext_vector_type(8))) short;   // 8 bf16 (4 VGPRs)
using float4v = __attribute__((ext_vector_type(4))) float;   // 4 fp32

// ---- fp32 -> bf16 round-to-nearest-even ----
__device__ __forceinline__ unsigned short f2b(float f) {
    union { float f; unsigned int u; } v; v.f = f;
    unsigned int u = v.u;
    unsigned int r = (u + 0x7FFFu + ((u >> 16) & 1u)) >> 16;
    return (unsigned short)r;
}

__device__ __forceinline__ float sigmoidf_(float x) {
    return __fdividef(1.0f, 1.0f + __expf(-x));
}
__device__ __forceinline__ float tanhf_(float x) {
    float e = __expf(-2.0f * fabsf(x));
    float t = __fdividef(1.0f - e, 1.0f + e);
    return copysignf(t, x);
}

// ---- prep: cast weights/x to bf16, combine biases ----
__global__ void prep_kernel(const float* __restrict__ x,
                            const float* __restrict__ wih0, const float* __restrict__ whh0,
                            const float* __restrict__ bih0, const float* __restrict__ bhh0,
                            const float* __restrict__ wih1, const float* __restrict__ whh1,
                            const float* __restrict__ bih1, const float* __restrict__ bhh1,
                            unsigned short* __restrict__ whh0_b, unsigned short* __restrict__ wih0_b,
                            unsigned short* __restrict__ whh1_b, unsigned short* __restrict__ wih1_b,
                            float* __restrict__ bias0, float* __restrict__ bias1,
                            unsigned short* __restrict__ xb) {
    int i = blockIdx.x * blockDim.x + threadIdx.x;
    if (i < B_SZ * S_LEN * C_IN) xb[i] = f2b(x[i]);           // (B,S,C) flat copy
    if (i < 4 * HDIM * HDIM) {                                 // 65536
        whh0_b[i] = f2b(whh0[i]);
        whh1_b[i] = f2b(whh1[i]);
        wih1_b[i] = f2b(wih1[i]);
    }
    if (i < 4 * HDIM * C_IN) wih0_b[i] = f2b(wih0[i]);         // 32768
    if (i < 4 * HDIM) {                                        // 512
        bias0[i] = bih0[i] + bhh0[i];
        bias1[i] = bih1[i] + bhh1[i];
    }
}

// ---- persistent recurrence kernel, one per layer ----
// MFMA 16x16x32 bf16 layouts (guide §3, m89/m91-verified):
//   A[m = lane&15][k = (lane>>4)*8 + j]   (short8, j=0..7, k-contiguous 16B)
//   B[k = (lane>>4)*8 + j][n = lane&15] == W[n][k] read as 16B row chunk
//   D[m = 4*(lane>>4)+reg][n = lane&15]
// Wave w (of 8) owns gate tiles n0 = g*128 + 16w for g=0..3 (i,f,g,o on the
// same j-slice) -> elementwise update is in-register; c persists in D-layout.
template<int KIN>
__global__ __launch_bounds__(512, 2)
void lstm_rec(const unsigned short* __restrict__ in_seq,   // KIN=64: xb (B,S,C); KIN=128: y1 (S,B,H), bf16
              const unsigned short* __restrict__ wih_b,    // (512, KIN) bf16
              const unsigned short* __restrict__ whh_b,    // (512, 128) bf16
              const float* __restrict__ bias,              // (512,) fp32 (bih+bhh)
              unsigned short* __restrict__ y_out,          // (S,B,H) bf16 or null
              float* __restrict__ final_out) {             // (B,H) fp32 or null
    constexpr int NKIN = KIN / 32;

    // h_{t-1} bf16, swizzled: element (row i, k) at [(k>>3)*128 + i*8 + (k&7)]
    // -> A-frag read for (kk,q,r) is 16B at [((kk*4+q)*16 + r)*8], i.e. lane-
    // consecutive ds_read_b128 (conflict-free pattern).
    __shared__ __align__(16) unsigned short hbuf[16 * HDIM];

    const int tid = threadIdx.x;
    const int w   = tid >> 6;     // wave 0..7
    const int L   = tid & 63;
    const int q   = L >> 4;       // quad 0..3
    const int r   = L & 15;
    const int boff = blockIdx.x * 16;
    const int j0   = w * 16;      // wave's hidden-slice

    // ---- preload weights into registers (once) ----
    short8 whh[4][4];
    short8 wih[4][NKIN];
    float  bias_s[4];
#pragma unroll
    for (int g = 0; g < 4; ++g) {
        const int nrow = g * HDIM + j0 + r;   // gate-row in (512 x K) weight
#pragma unroll
        for (int kk = 0; kk < 4; ++kk)
            whh[g][kk] = *(const short8*)(whh_b + (size_t)nrow * HDIM + kk * 32 + q * 8);
#pragma unroll
        for (int kk = 0; kk < NKIN; ++kk)
            wih[g][kk] = *(const short8*)(wih_b + (size_t)nrow * KIN + kk * 32 + q * 8);
        bias_s[g] = bias[g * HDIM + j0 + r];
    }

    // ---- init state: h0 = c0 = 0 ----
    for (int idx = tid; idx < 16 * HDIM; idx += 512) hbuf[idx] = 0;
    float cf[4] = {0.f, 0.f, 0.f, 0.f};
    __syncthreads();

    auto load_in = [&](int t, short8* dst) {
#pragma unroll
        for (int kk = 0; kk < NKIN; ++kk) {
            size_t idx;
            if constexpr (KIN == C_IN)
                idx = ((size_t)(boff + r) * S_LEN + t) * C_IN + kk * 32 + q * 8;   // (B,S,C)
            else
                idx = ((size_t)t * B_SZ + boff + r) * HDIM + kk * 32 + q * 8;      // (S,B,H)
            dst[kk] = *(const short8*)(in_seq + idx);
        }
    };

    short8 xcur[NKIN], xnxt[NKIN];
    load_in(0, xcur);

    const int j = j0 + r;                         // this lane's hidden index
    const int chunkbase = (j >> 3) * 128 + (j & 7);

    for (int t = 0; t < S_LEN; ++t) {
        // A-frags of h_{t-1} (consecutive b128, conflict-free)
        short8 hfrag[4];
#pragma unroll
        for (int kk = 0; kk < 4; ++kk)
            hfrag[kk] = *(const short8*)(hbuf + ((kk * 4 + q) * 16 + r) * 8);

        // prefetch next step's input (hides ~900cy HBM/L2 latency)
        const int tn = (t + 1 < S_LEN) ? t + 1 : t;
        load_in(tn, xnxt);

        // gates = bias + h*Whh^T + x*Wih^T  (4 independent MFMA chains)
        float4v acc[4];
#pragma unroll
        for (int g = 0; g < 4; ++g) {
            float4v a = {bias_s[g], bias_s[g], bias_s[g], bias_s[g]};
#pragma unroll
            for (int kk = 0; kk < 4; ++kk)
                a = __builtin_amdgcn_mfma_f32_16x16x32_bf16(hfrag[kk], whh[g][kk], a, 0, 0, 0);
#pragma unroll
            for (int kk = 0; kk < NKIN; ++kk)
                a = __builtin_amdgcn_mfma_f32_16x16x32_bf16(xcur[kk], wih[g][kk], a, 0, 0, 0);
            acc[g] = a;
        }

        __syncthreads();   // all waves consumed h_{t-1}; safe to overwrite hbuf

        // elementwise LSTM update, in D-layout: lane holds rows 4q+rr, col j
#pragma unroll
        for (int rr = 0; rr < 4; ++rr) {
            const float iv = sigmoidf_(acc[0][rr]);
            const float fv = sigmoidf_(acc[1][rr]);
            const float gv = tanhf_(acc[2][rr]);
            const float ov = sigmoidf_(acc[3][rr]);
            cf[rr] = fv * cf[rr] + iv * gv;
            const float hv = ov * tanhf_(cf[rr]);
            const unsigned short hb = f2b(hv);
            const int irow = 4 * q + rr;
            hbuf[chunkbase + irow * 8] = hb;
            if (y_out)
                y_out[((size_t)t * B_SZ + boff + irow) * HDIM + j] = hb;
            if (final_out && t == S_LEN - 1)
                final_out[(size_t)(boff + irow) * HDIM + j] = hv;
        }
        __syncthreads();   // new h visible to all waves

#pragma unroll
        for (int kk = 0; kk < NKIN; ++kk) xcur[kk] = xnxt[kk];
    }
}

// ---- workspace layout (bytes) ----
//      0 : Whh0 bf16  (512x128)  131072
// 131072 : Wih0 bf16  (512x 64)   65536
// 196608 : Whh1 bf16  (512x128)  131072
// 327680 : Wih1 bf16  (512x128)  131072
// 458752 : bias0 f32  (512)        2048
// 460800 : bias1 f32  (512)        2048
// 524288 : xb  bf16   (B,S,C)  16777216
// 17301504: y1 bf16   (S,B,H)  33554432   -> total ~48.5 MB

extern "C" void kernel_launch(void* const* d_in, const int* in_sizes, int n_in,
                              void* d_out, int out_size, void* d_ws, size_t ws_size,
                              hipStream_t stream) {
    const float* x    = (const float*)d_in[0];
    const float* wih0 = (const float*)d_in[1];
    const float* whh0 = (const float*)d_in[2];
    const float* bih0 = (const float*)d_in[3];
    const float* bhh0 = (const float*)d_in[4];
    const float* wih1 = (const float*)d_in[5];
    const float* whh1 = (const float*)d_in[6];
    const float* bih1 = (const float*)d_in[7];
    const float* bhh1 = (const float*)d_in[8];

    char* ws = (char*)d_ws;
    unsigned short* whh0_b = (unsigned short*)(ws + 0);
    unsigned short* wih0_b = (unsigned short*)(ws + 131072);
    unsigned short* whh1_b = (unsigned short*)(ws + 196608);
    unsigned short* wih1_b = (unsigned short*)(ws + 327680);
    float*          bias0  = (float*)(ws + 458752);
    float*          bias1  = (float*)(ws + 460800);
    unsigned short* xb     = (unsigned short*)(ws + 524288);
    unsigned short* y1     = (unsigned short*)(ws + 17301504);

    prep_kernel<<<(B_SZ * S_LEN * C_IN + 255) / 256, 256, 0, stream>>>(
        x, wih0, whh0, bih0, bhh0, wih1, whh1, bih1, bhh1,
        whh0_b, wih0_b, whh1_b, wih1_b, bias0, bias1, xb);

    lstm_rec<C_IN><<<dim3(B_SZ / 16), dim3(512), 0, stream>>>(
        xb, wih0_b, whh0_b, bias0, y1, nullptr);

    lstm_rec<HDIM><<<dim3(B_SZ / 16), dim3(512), 0, stream>>>(
        y1, wih1_b, whh1_b, bias1, nullptr, (float*)d_out);
}

// Round 2
// 1020.164 us; speedup vs baseline: 1.9415x; 1.9415x over previous
//
#include <hip/hip_runtime.h>
#include <cstdint>
#include <cstddef>

// LSTM B=256,S=512,C=64,H=128, 2 layers, gates i,f,g,o (torch order).
// Round 2: single pipelined kernel, 32 blocks x 512 threads.
//   blocks 0-15  : layer 0, batch rows 16b..16b+15, fused x*Wih0^T
//   blocks 16-31 : layer 1, consumes y1 in 16-step chunks via agent-scope flags
// Per step: double-buffered h in LDS -> ONE __syncthreads per step.
// Weights register-resident bf16 B-fragments; c-state fp32 in D-layout regs.

#define S_LEN 512
#define B_SZ  256
#define C_IN  64
#define HDIM  128
#define CH    16            // handoff chunk (steps)

using short8  = __attribute__((ext_vector_type(8))) short;   // 8 bf16
using float4v = __attribute__((ext_vector_type(4))) float;

__device__ __forceinline__ unsigned short f2b(float f) {
    union { float f; unsigned int u; } v; v.f = f;
    unsigned int u = v.u;
    return (unsigned short)((u + 0x7FFFu + ((u >> 16) & 1u)) >> 16);
}
__device__ __forceinline__ float sigmoidf_(float x) {
    return __fdividef(1.0f, 1.0f + __expf(-x));
}
__device__ __forceinline__ float tanhf_(float x) {
    // 1 - 2/(1+e^{2x}); exp overflow -> inf -> correct +/-1 saturation
    return 1.0f - __fdividef(2.0f, 1.0f + __expf(2.0f * x));
}

// ---- prep: cast weights/x to bf16, combine biases ----
__global__ void prep_kernel(const float* __restrict__ x,
                            const float* __restrict__ wih0, const float* __restrict__ whh0,
                            const float* __restrict__ bih0, const float* __restrict__ bhh0,
                            const float* __restrict__ wih1, const float* __restrict__ whh1,
                            const float* __restrict__ bih1, const float* __restrict__ bhh1,
                            unsigned short* __restrict__ whh0_b, unsigned short* __restrict__ wih0_b,
                            unsigned short* __restrict__ whh1_b, unsigned short* __restrict__ wih1_b,
                            float* __restrict__ bias0, float* __restrict__ bias1,
                            unsigned short* __restrict__ xb) {
    int i = blockIdx.x * blockDim.x + threadIdx.x;
    if (i < B_SZ * S_LEN * C_IN) xb[i] = f2b(x[i]);
    if (i < 4 * HDIM * HDIM) {
        whh0_b[i] = f2b(whh0[i]);
        whh1_b[i] = f2b(whh1[i]);
        wih1_b[i] = f2b(wih1[i]);
    }
    if (i < 4 * HDIM * C_IN) wih0_b[i] = f2b(wih0[i]);
    if (i < 4 * HDIM) {
        bias0[i] = bih0[i] + bhh0[i];
        bias1[i] = bih1[i] + bhh1[i];
    }
}

// ---- one layer's recurrence (runs in half the grid) ----
// MFMA 16x16x32 bf16 frags (verified round 1):
//   A[m=lane&15][k=(lane>>4)*8+j], B == W[n=lane&15][k] 16B row chunk,
//   D[m=4*(lane>>4)+reg][n=lane&15]
template<int KIN, bool IS_L0>
__device__ __forceinline__ void lstm_layer(
    unsigned short* hbuf,                         // 2 x 2048 shorts in LDS
    const unsigned short* __restrict__ in_seq,    // L0: xb (B,S,C); L1: y1 (S,B,H)
    const unsigned short* __restrict__ wih_b,     // (512,KIN) bf16
    const unsigned short* __restrict__ whh_b,     // (512,128) bf16
    const float* __restrict__ bias,               // (512,) fp32
    unsigned short* __restrict__ y1,              // L0 out (S,B,H) bf16
    float* __restrict__ final_out,                // L1 out (B,H) fp32
    int* __restrict__ flags, int blk) {
    constexpr int NKIN = KIN / 32;
    const int tid = threadIdx.x;
    const int w = tid >> 6, L = tid & 63, q = L >> 4, r = L & 15;
    const int boff = blk * 16, j0 = w * 16;

    // register-resident weights
    short8 whh[4][4], wih[4][NKIN];
    float bias_s[4];
#pragma unroll
    for (int g = 0; g < 4; ++g) {
        const int nrow = g * HDIM + j0 + r;
#pragma unroll
        for (int kk = 0; kk < 4; ++kk)
            whh[g][kk] = *(const short8*)(whh_b + (size_t)nrow * HDIM + kk * 32 + q * 8);
#pragma unroll
        for (int kk = 0; kk < NKIN; ++kk)
            wih[g][kk] = *(const short8*)(wih_b + (size_t)nrow * KIN + kk * 32 + q * 8);
        bias_s[g] = bias[g * HDIM + j0 + r];
    }

    for (int idx = tid; idx < 2048; idx += 512) hbuf[idx] = 0;   // h_{-1} = 0
    float cf[4] = {0.f, 0.f, 0.f, 0.f};

    // per-lane input pointer, bumped by stride each step
    const unsigned short* p;
    size_t stride;
    if constexpr (IS_L0) { p = in_seq + ((size_t)(boff + r) * S_LEN) * C_IN + q * 8; stride = C_IN; }
    else                 { p = in_seq + (size_t)(boff + r) * HDIM + q * 8; stride = (size_t)B_SZ * HDIM; }

    if constexpr (!IS_L0) {
        if (tid == 0)
            while (__hip_atomic_load(flags + 0, __ATOMIC_ACQUIRE, __HIP_MEMORY_SCOPE_AGENT) == 0)
                __builtin_amdgcn_s_sleep(8);
    }
    __syncthreads();   // covers hbuf zero + initial flag gate

    short8 xcur[NKIN], xnxt[NKIN];
#pragma unroll
    for (int kk = 0; kk < NKIN; ++kk) xcur[kk] = *(const short8*)(p + kk * 32);
    p += stride;

    // coalesced y1 store mapping (L0): thread(tid<256) -> row ii, col-chunk cc
    const int cc = tid & 15, ii = (tid & 255) >> 4;
    unsigned short* yst = y1 + (size_t)(boff + ii) * HDIM + cc * 8;

    const int j = j0 + r;
    const int chunkbase = (j >> 3) * 128 + (j & 7);

    auto step = [&](unsigned short* cur, unsigned short* nxt, int t) {
        // h_{t-1} A-frags: consecutive-lane ds_read_b128, conflict-free
        short8 hfrag[4];
#pragma unroll
        for (int kk = 0; kk < 4; ++kk)
            hfrag[kk] = *(const short8*)(cur + ((kk * 4 + q) * 16 + r) * 8);

        // prefetch next input (chunk-gated for L1)
        if (t < S_LEN - 1) {
            if constexpr (!IS_L0) {
                if (((t + 1) & (CH - 1)) == 0) {
                    if (tid == 0)
                        while (__hip_atomic_load(flags + ((t + 1) / CH), __ATOMIC_ACQUIRE,
                                                 __HIP_MEMORY_SCOPE_AGENT) == 0)
                            __builtin_amdgcn_s_sleep(8);
                    __syncthreads();
                }
            }
#pragma unroll
            for (int kk = 0; kk < NKIN; ++kk) xnxt[kk] = *(const short8*)(p + kk * 32);
        }
        p += stride;

        // gates = bias + h*Whh^T + x*Wih^T
        float4v acc[4];
#pragma unroll
        for (int g = 0; g < 4; ++g) {
            float4v a = {bias_s[g], bias_s[g], bias_s[g], bias_s[g]};
#pragma unroll
            for (int kk = 0; kk < 4; ++kk)
                a = __builtin_amdgcn_mfma_f32_16x16x32_bf16(hfrag[kk], whh[g][kk], a, 0, 0, 0);
#pragma unroll
            for (int kk = 0; kk < NKIN; ++kk)
                a = __builtin_amdgcn_mfma_f32_16x16x32_bf16(xcur[kk], wih[g][kk], a, 0, 0, 0);
            acc[g] = a;
        }

        // elementwise update in D-layout (lane: rows 4q+rr, col j)
#pragma unroll
        for (int rr = 0; rr < 4; ++rr) {
            const float iv = sigmoidf_(acc[0][rr]);
            const float fv = sigmoidf_(acc[1][rr]);
            const float gv = tanhf_(acc[2][rr]);
            const float ov = sigmoidf_(acc[3][rr]);
            cf[rr] = fv * cf[rr] + iv * gv;
            const float hv = ov * tanhf_(cf[rr]);
            nxt[chunkbase + (4 * q + rr) * 8] = f2b(hv);
            if constexpr (!IS_L0) {
                if (t == S_LEN - 1)
                    final_out[(size_t)(boff + 4 * q + rr) * HDIM + j] = hv;
            }
        }
        __syncthreads();   // h_t visible; (one barrier/step: double-buffered)

        if constexpr (IS_L0) {
            // coalesced copy h_t -> y1[t] (256B segments per 16 lanes)
            if (tid < 256)
                *(short8*)yst = *(const short8*)(nxt + cc * 128 + ii * 8);
            yst += (size_t)B_SZ * HDIM;
            if ((t & (CH - 1)) == (CH - 1)) {
                __threadfence();          // each thread's y1 stores visible device-wide
                __syncthreads();
                if (tid == 0)
                    __hip_atomic_store(flags + (t / CH), 1, __ATOMIC_RELEASE,
                                       __HIP_MEMORY_SCOPE_AGENT);
            }
        }
#pragma unroll
        for (int kk = 0; kk < NKIN; ++kk) xcur[kk] = xnxt[kk];
    };

    unsigned short* b0 = hbuf;
    unsigned short* b1 = hbuf + 2048;
    for (int t = 0; t < S_LEN; t += 2) { step(b0, b1, t); step(b1, b0, t + 1); }
}

__global__ __launch_bounds__(512, 2)
void lstm_pipe(const unsigned short* __restrict__ xb,
               const unsigned short* __restrict__ wih0_b, const unsigned short* __restrict__ whh0_b,
               const float* __restrict__ bias0,
               const unsigned short* __restrict__ wih1_b, const unsigned short* __restrict__ whh1_b,
               const float* __restrict__ bias1,
               unsigned short* __restrict__ y1, float* __restrict__ out,
               int* __restrict__ flags) {
    __shared__ __align__(16) unsigned short hbuf[2 * 2048];
    if (blockIdx.x < 16)
        lstm_layer<C_IN, true>(hbuf, xb, wih0_b, whh0_b, bias0, y1, nullptr, flags, blockIdx.x);
    else
        lstm_layer<HDIM, false>(hbuf, y1, wih1_b, whh1_b, bias1, nullptr, out, flags, blockIdx.x - 16);
}

// ---- workspace layout (bytes) ----
//       0 : whh0_b 131072
//  131072 : wih0_b  65536
//  196608 : whh1_b 131072
//  327680 : wih1_b 131072
//  458752 : bias0    2048
//  460800 : bias1    2048
//  462848 : flags     128  (32 ints, memset to 0 each launch)
//  524288 : xb   16777216
// 17301504: y1   33554432

extern "C" void kernel_launch(void* const* d_in, const int* in_sizes, int n_in,
                              void* d_out, int out_size, void* d_ws, size_t ws_size,
                              hipStream_t stream) {
    const float* x    = (const float*)d_in[0];
    const float* wih0 = (const float*)d_in[1];
    const float* whh0 = (const float*)d_in[2];
    const float* bih0 = (const float*)d_in[3];
    const float* bhh0 = (const float*)d_in[4];
    const float* wih1 = (const float*)d_in[5];
    const float* whh1 = (const float*)d_in[6];
    const float* bih1 = (const float*)d_in[7];
    const float* bhh1 = (const float*)d_in[8];

    char* ws = (char*)d_ws;
    unsigned short* whh0_b = (unsigned short*)(ws + 0);
    unsigned short* wih0_b = (unsigned short*)(ws + 131072);
    unsigned short* whh1_b = (unsigned short*)(ws + 196608);
    unsigned short* wih1_b = (unsigned short*)(ws + 327680);
    float*          bias0  = (float*)(ws + 458752);
    float*          bias1  = (float*)(ws + 460800);
    int*            flags  = (int*)(ws + 462848);
    unsigned short* xb     = (unsigned short*)(ws + 524288);
    unsigned short* y1     = (unsigned short*)(ws + 17301504);

    hipMemsetAsync(flags, 0, 128, stream);

    prep_kernel<<<(B_SZ * S_LEN * C_IN + 255) / 256, 256, 0, stream>>>(
        x, wih0, whh0, bih0, bhh0, wih1, whh1, bih1, bhh1,
        whh0_b, wih0_b, whh1_b, wih1_b, bias0, bias1, xb);

    lstm_pipe<<<dim3(32), dim3(512), 0, stream>>>(
        xb, wih0_b, whh0_b, bias0, wih1_b, whh1_b, bias1, y1, (float*)d_out, flags);
}

// Round 3
// 734.900 us; speedup vs baseline: 2.6952x; 1.3882x over previous
//
#include <hip/hip_runtime.h>
#include <cstdint>
#include <cstddef>

// LSTM B=256,S=512,C=64,H=128, 2 layers, gates i,f,g,o (torch order).
// Round 3: M-split. 64 blocks x 512 threads:
//   blocks  0-31 : layer 0, 8 batch rows each (MFMA M=16 half-used)
//   blocks 32-63 : layer 1, consumes y1 in 16-step chunks via tokened flags
// Batch rows are permuted into tile rows {m : (m&3)<2} so the elementwise
// update touches rr=0,1 only -> per-wave elementwise issue count halves
// (this is the point: exec-masking alone would NOT halve issue cost).
// One __syncthreads per step (double-buffered h in LDS). Weights live in
// register-file bf16 B-fragments; c-state fp32 in D-layout registers.

#define S_LEN 512
#define B_SZ  256
#define C_IN  64
#define HDIM  128
#define CH    16
#define NBLK  32            // blocks per layer, 8 rows each

using short8  = __attribute__((ext_vector_type(8))) short;   // 8 bf16
using float4v = __attribute__((ext_vector_type(4))) float;

__device__ __forceinline__ unsigned short f2b(float f) {
    union { float f; unsigned int u; } v; v.f = f;
    unsigned int u = v.u;
    return (unsigned short)((u + 0x7FFFu + ((u >> 16) & 1u)) >> 16);
}
// lean activations: sigma = rcp(1+exp2(-x*log2e)), tanh = 1-2*rcp(1+exp2(2x*log2e))
__device__ __forceinline__ float sig_(float x) {
    return __builtin_amdgcn_rcpf(1.0f + __builtin_amdgcn_exp2f(x * -1.442695041f));
}
__device__ __forceinline__ float tanh_(float x) {
    return 1.0f - 2.0f * __builtin_amdgcn_rcpf(1.0f + __builtin_amdgcn_exp2f(x * 2.885390082f));
}

__global__ void prep_kernel(const float* __restrict__ x,
                            const float* __restrict__ wih0, const float* __restrict__ whh0,
                            const float* __restrict__ bih0, const float* __restrict__ bhh0,
                            const float* __restrict__ wih1, const float* __restrict__ whh1,
                            const float* __restrict__ bih1, const float* __restrict__ bhh1,
                            unsigned short* __restrict__ whh0_b, unsigned short* __restrict__ wih0_b,
                            unsigned short* __restrict__ whh1_b, unsigned short* __restrict__ wih1_b,
                            float* __restrict__ bias0, float* __restrict__ bias1,
                            unsigned short* __restrict__ xb) {
    int i = blockIdx.x * blockDim.x + threadIdx.x;
    if (i < B_SZ * S_LEN * C_IN) xb[i] = f2b(x[i]);
    if (i < 4 * HDIM * HDIM) {
        whh0_b[i] = f2b(whh0[i]);
        whh1_b[i] = f2b(whh1[i]);
        wih1_b[i] = f2b(wih1[i]);
    }
    if (i < 4 * HDIM * C_IN) wih0_b[i] = f2b(wih0[i]);
    if (i < 4 * HDIM) {
        bias0[i] = bih0[i] + bhh0[i];
        bias1[i] = bih1[i] + bhh1[i];
    }
}

// MFMA 16x16x32 bf16 frags (verified rounds 1-2):
//   A[m=lane&15][k=(lane>>4)*8+j], B == W[n=lane&15][k] 16B row chunk,
//   D[m=4*(lane>>4)+reg][n=lane&15]
template<int KIN, bool IS_L0>
__device__ __forceinline__ void lstm_layer(
    unsigned short* hbuf,                         // 2 x 2048 shorts in LDS
    const unsigned short* __restrict__ in_seq,    // L0: xb (B,S,C); L1: y1 (S,B,H)
    const unsigned short* __restrict__ wih_b,     // (512,KIN) bf16
    const unsigned short* __restrict__ whh_b,     // (512,128) bf16
    const float* __restrict__ bias,               // (512,) fp32
    unsigned short* __restrict__ y1,              // L0 out (S,B,H) bf16
    float* __restrict__ final_out,                // L1 out (B,H) fp32
    int* __restrict__ flags, int blk) {
    constexpr int NKIN = KIN / 32;
    const int tid = threadIdx.x;
    const int w = tid >> 6, L = tid & 63, q = L >> 4, r = L & 15;
    const int boff = blk * 8, j0 = w * 16;
    // tile row r carries batch row boff + rowload(r); valid tile rows (m&3)<2
    const int rowload = (r >> 2) * 2 + (r & 1);

    // register-resident weights (B-fragments; n depends on r only)
    short8 whh[4][4], wih[4][NKIN];
    float bias_s[4];
#pragma unroll
    for (int g = 0; g < 4; ++g) {
        const int nrow = g * HDIM + j0 + r;
#pragma unroll
        for (int kk = 0; kk < 4; ++kk)
            whh[g][kk] = *(const short8*)(whh_b + (size_t)nrow * HDIM + kk * 32 + q * 8);
#pragma unroll
        for (int kk = 0; kk < NKIN; ++kk)
            wih[g][kk] = *(const short8*)(wih_b + (size_t)nrow * KIN + kk * 32 + q * 8);
        bias_s[g] = bias[g * HDIM + j0 + r];
    }

    for (int idx = tid; idx < 2 * 2048; idx += 512) hbuf[idx] = 0;  // h_{-1}=0 (both buffers)
    float cf[2] = {0.f, 0.f};

    // per-lane input pointer (next load position), bumped by stride per step
    const unsigned short* p;
    size_t stride;
    if constexpr (IS_L0) {
        p = in_seq + ((size_t)(boff + rowload) * S_LEN) * C_IN + q * 8;
        stride = C_IN;
    } else {
        p = in_seq + (size_t)(boff + rowload) * HDIM + q * 8;
        stride = (size_t)B_SZ * HDIM;
    }

    if constexpr (!IS_L0) {
        if (tid == 0)
            while (__hip_atomic_load(flags + blk * 32, __ATOMIC_ACQUIRE,
                                     __HIP_MEMORY_SCOPE_AGENT) != 1)
                __builtin_amdgcn_s_sleep(8);
    }
    __syncthreads();   // covers hbuf zero + initial chunk gate

    short8 xA[NKIN], xB[NKIN];
#pragma unroll
    for (int kk = 0; kk < NKIN; ++kk) xA[kk] = *(const short8*)(p + kk * 32);
    p += stride;

    // coalesced y1 store mapping (L0): thread tid<128 -> batch row ii, col-chunk cc
    const int cc = tid & 15, ii = (tid & 127) >> 4;
    const int mii = 4 * (ii >> 1) + (ii & 1);          // tile row holding batch row ii
    unsigned short* yst = y1 + (size_t)(boff + ii) * HDIM + cc * 8;

    const int j = j0 + r;
    const int chunkbase = (j >> 3) * 128 + (j & 7);
    float* fout = final_out ? final_out + (size_t)(boff + 2 * q) * HDIM + j : nullptr;

    auto step = [&](unsigned short* cur, unsigned short* nxt, short8* xc, short8* xn, int t) {
        // h_{t-1} A-frags
        short8 hfrag[4];
#pragma unroll
        for (int kk = 0; kk < 4; ++kk)
            hfrag[kk] = *(const short8*)(cur + ((kk * 4 + q) * 16 + r) * 8);

        // prefetch next input (chunk-gated for L1, tokened flags: replay-safe)
        if (t < S_LEN - 1) {
            if constexpr (!IS_L0) {
                if (((t + 1) & (CH - 1)) == 0) {
                    const int ch = (t + 1) / CH;
                    if (tid == 0)
                        while (__hip_atomic_load(flags + blk * 32 + ch, __ATOMIC_ACQUIRE,
                                                 __HIP_MEMORY_SCOPE_AGENT) != ch + 1)
                            __builtin_amdgcn_s_sleep(8);
                    __syncthreads();
                }
            }
#pragma unroll
            for (int kk = 0; kk < NKIN; ++kk) xn[kk] = *(const short8*)(p + kk * 32);
        }
        p += stride;

        // gates = bias + h*Whh^T + x*Wih^T
        float4v acc[4];
#pragma unroll
        for (int g = 0; g < 4; ++g) {
            float4v a = {bias_s[g], bias_s[g], bias_s[g], bias_s[g]};
#pragma unroll
            for (int kk = 0; kk < 4; ++kk)
                a = __builtin_amdgcn_mfma_f32_16x16x32_bf16(hfrag[kk], whh[g][kk], a, 0, 0, 0);
#pragma unroll
            for (int kk = 0; kk < NKIN; ++kk)
                a = __builtin_amdgcn_mfma_f32_16x16x32_bf16(xc[kk], wih[g][kk], a, 0, 0, 0);
            acc[g] = a;
        }

        // elementwise update: ONLY rr=0,1 (valid tile rows m=4q+rr, batch 2q+rr)
#pragma unroll
        for (int rr = 0; rr < 2; ++rr) {
            const float iv = sig_(acc[0][rr]);
            const float fv = sig_(acc[1][rr]);
            const float gv = tanh_(acc[2][rr]);
            const float ov = sig_(acc[3][rr]);
            cf[rr] = fv * cf[rr] + iv * gv;
            const float hv = ov * tanh_(cf[rr]);
            nxt[chunkbase + (4 * q + rr) * 8] = f2b(hv);
            if constexpr (!IS_L0) {
                if (t == S_LEN - 1) fout[rr * HDIM] = hv;
            }
        }
        __syncthreads();   // h_t visible (one barrier/step: double buffer)

        if constexpr (IS_L0) {
            // coalesced h_t -> y1[t] (8 rows x 256B), threads 0..127
            if (tid < 128)
                *(short8*)yst = *(const short8*)(nxt + cc * 128 + mii * 8);
            yst += (size_t)B_SZ * HDIM;
            if ((t & (CH - 1)) == (CH - 1)) {
                __threadfence();
                __syncthreads();
                if (tid == 0) {
                    const int ch = t / CH;
                    __hip_atomic_store(flags + blk * 32 + ch, ch + 1, __ATOMIC_RELEASE,
                                       __HIP_MEMORY_SCOPE_AGENT);
                }
            }
        }
    };

    unsigned short* b0 = hbuf;
    unsigned short* b1 = hbuf + 2048;
    for (int t = 0; t < S_LEN; t += 2) {
        step(b0, b1, xA, xB, t);       // consumes xA, prefetches xB
        step(b1, b0, xB, xA, t + 1);   // consumes xB, prefetches xA
    }
}

__global__ __launch_bounds__(512, 2)
void lstm_pipe(const unsigned short* __restrict__ xb,
               const unsigned short* __restrict__ wih0_b, const unsigned short* __restrict__ whh0_b,
               const float* __restrict__ bias0,
               const unsigned short* __restrict__ wih1_b, const unsigned short* __restrict__ whh1_b,
               const float* __restrict__ bias1,
               unsigned short* __restrict__ y1, float* __restrict__ out,
               int* __restrict__ flags) {
    __shared__ __align__(16) unsigned short hbuf[2 * 2048];
    if (blockIdx.x < NBLK)
        lstm_layer<C_IN, true>(hbuf, xb, wih0_b, whh0_b, bias0, y1, nullptr, flags, blockIdx.x);
    else
        lstm_layer<HDIM, false>(hbuf, y1, wih1_b, whh1_b, bias1, nullptr, out, flags,
                                blockIdx.x - NBLK);
}

// ---- workspace layout (bytes) ----
//       0 : whh0_b 131072
//  131072 : wih0_b  65536
//  196608 : whh1_b 131072
//  327680 : wih1_b 131072
//  458752 : bias0    2048
//  460800 : bias1    2048
//  462848 : flags    4096  (32 blocks x 32 chunks, memset 0 each launch)
//  524288 : xb   16777216
// 17301504: y1   33554432

extern "C" void kernel_launch(void* const* d_in, const int* in_sizes, int n_in,
                              void* d_out, int out_size, void* d_ws, size_t ws_size,
                              hipStream_t stream) {
    const float* x    = (const float*)d_in[0];
    const float* wih0 = (const float*)d_in[1];
    const float* whh0 = (const float*)d_in[2];
    const float* bih0 = (const float*)d_in[3];
    const float* bhh0 = (const float*)d_in[4];
    const float* wih1 = (const float*)d_in[5];
    const float* whh1 = (const float*)d_in[6];
    const float* bih1 = (const float*)d_in[7];
    const float* bhh1 = (const float*)d_in[8];

    char* ws = (char*)d_ws;
    unsigned short* whh0_b = (unsigned short*)(ws + 0);
    unsigned short* wih0_b = (unsigned short*)(ws + 131072);
    unsigned short* whh1_b = (unsigned short*)(ws + 196608);
    unsigned short* wih1_b = (unsigned short*)(ws + 327680);
    float*          bias0  = (float*)(ws + 458752);
    float*          bias1  = (float*)(ws + 460800);
    int*            flags  = (int*)(ws + 462848);
    unsigned short* xb     = (unsigned short*)(ws + 524288);
    unsigned short* y1     = (unsigned short*)(ws + 17301504);

    hipMemsetAsync(flags, 0, 4096, stream);

    prep_kernel<<<(B_SZ * S_LEN * C_IN + 255) / 256, 256, 0, stream>>>(
        x, wih0, whh0, bih0, bhh0, wih1, whh1, bih1, bhh1,
        whh0_b, wih0_b, whh1_b, wih1_b, bias0, bias1, xb);

    lstm_pipe<<<dim3(2 * NBLK), dim3(512), 0, stream>>>(
        xb, wih0_b, whh0_b, bias0, wih1_b, whh1_b, bias1, y1, (float*)d_out, flags);
}